// Round 3
// baseline (179.482 us; speedup 1.0000x reference)
//
#include <hip/hip_runtime.h>

#define N_NODES 100000
#define N_EDGES 3200000
#define NB 1024                        // buckets: 4 sortagg/agg2 blocks per CU
#define BKN 98                         // nodes per bucket (1024*98=100352)
#define RSZ 3968                       // record window (mean 3136, +14.9 sigma)
#define TILE 6250
#define NTILES 512                     // 512*6250 == 3.2M exactly; 2 blocks/CU
#define MAXIT 13                       // ceil(TILE/512)
#define MAXB 8                         // ceil(RSZ/512)
#define PRN 196                        // proj nodes per scatter block (512*196)

typedef int   i32x4 __attribute__((ext_vector_type(4)));
typedef float f32x4 __attribute__((ext_vector_type(4)));

// ---------------------------------------------------------------------------
// 3 kernels + memset (proj fused into scatter; round-1 showed full fusion
// regresses 3x, so kernel boundaries stay for the two gather phases):
//   memset gcur
//   k_projscatter : proj1 (x-loads issued first, FMAs after edge loads are
//                   in flight) + tile counting-sort scatter, wave-shuffle scan
//   k_sortagg1    : per-bucket LDS sort + layer-1 agg, 8 lanes/node
//                   (4-way edge parallel x 2-way channel), NT recs/q1b reads
//   k_agg2out     : layer-2 agg, int4 recs reads + LDS atomicAdd
// ---------------------------------------------------------------------------

__device__ __forceinline__ float bf2f_lo(unsigned int w) {
  return __uint_as_float(w << 16);
}
__device__ __forceinline__ float bf2f_hi(unsigned int w) {
  return __uint_as_float(w & 0xFFFF0000u);
}
__device__ __forceinline__ unsigned short f2bf(float f) {
  unsigned int b = __float_as_uint(f);
  return (unsigned short)((b + 0x7FFFu + ((b >> 16) & 1u)) >> 16);
}

// proj + tile counting-sort scatter. 512 blocks x 512 = exactly 2/CU.
__global__ __launch_bounds__(512, 4) void k_projscatter(
    const float* __restrict__ x, const int* __restrict__ ei,
    const float* __restrict__ Wl1, const float* __restrict__ Wr1,
    const float* __restrict__ b1, unsigned short* __restrict__ p1h,
    float* __restrict__ q1b, int* __restrict__ gcur, int* __restrict__ recs) {
  __shared__ int hist[1024];   // counts -> exclusive scan (bucket starts)
  __shared__ int delta[NB];    // absolute_base - bstart per bucket
  __shared__ int wsum[8];
  __shared__ union {
    struct { float Wl[512], Wr[512], b[16]; } w;          // proj phase
    struct { int stage[TILE]; unsigned short bid[TILE + 6]; } s;  // scatter
  } u;
  const int t = threadIdx.x;
  const int kb = blockIdx.x;

  for (int i = t; i < 1024; i += 512) hist[i] = 0;
  u.w.Wl[t] = Wl1[t];
  u.w.Wr[t] = Wr1[t];
  if (t < 16) u.w.b[t] = b1[t];
  __syncthreads();

  // issue this block's x loads first; FMAs consume them after the edge
  // loads below are in flight (compiler schedules waitcnt at first use)
  const int n = kb * PRN + t;
  f32x4 xv[8];
  const bool do_proj = (t < PRN) && (n < N_NODES);
  if (do_proj) {
    const f32x4* xp = (const f32x4*)(x + (size_t)n * 32);
#pragma unroll
    for (int j = 0; j < 8; ++j) xv[j] = xp[j];
  }

  // edge load + LDS histogram rank (1 atomic/record)
  const int tb = kb * TILE;
  int rec[MAXIT], aux[MAXIT];  // aux = (bucket<<16) | rank
#pragma unroll
  for (int i = 0; i < MAXIT; ++i) {
    const int pos = t + i * 512;
    if (pos < TILE) {
      const int e = tb + pos;
      const int s = ei[e];
      const int d = ei[N_EDGES + e];
      const int k = (int)((unsigned)d / (unsigned)BKN);
      const int rank = atomicAdd(&hist[k], 1);
      rec[i] = ((d - k * BKN) << 17) | s;
      aux[i] = (k << 16) | rank;
    } else {
      aux[i] = -1;
    }
  }

  // proj compute + stores (overlaps edge-load latency drain)
  if (do_proj) {
    float pv[16], qv[16];
#pragma unroll
    for (int hh = 0; hh < 16; ++hh) {
      float a = 0.f, b = 0.f;
#pragma unroll
      for (int i = 0; i < 32; ++i) {
        const float xi = xv[i >> 2][i & 3];
        a = fmaf(xi, u.w.Wl[hh * 32 + i], a);
        b = fmaf(xi, u.w.Wr[hh * 32 + i], b);
      }
      pv[hh] = a;
      qv[hh] = b + u.w.b[hh];
    }
    unsigned int w[8];
#pragma unroll
    for (int j = 0; j < 8; ++j)
      w[j] = (unsigned int)f2bf(pv[2 * j]) |
             ((unsigned int)f2bf(pv[2 * j + 1]) << 16);
    uint4* pp = (uint4*)(p1h + (size_t)n * 16);
    pp[0] = make_uint4(w[0], w[1], w[2], w[3]);
    pp[1] = make_uint4(w[4], w[5], w[6], w[7]);
    float4* qp = (float4*)(q1b + (size_t)n * 16);
#pragma unroll
    for (int j = 0; j < 4; ++j)
      qp[j] =
          make_float4(qv[4 * j], qv[4 * j + 1], qv[4 * j + 2], qv[4 * j + 3]);
  }
  __syncthreads();

  // wave-shuffle exclusive scan of hist[1024] (2 barriers total)
  const int s0 = hist[2 * t], s1 = hist[2 * t + 1];
  const int sp = s0 + s1;
  int incl = sp;
#pragma unroll
  for (int o = 1; o < 64; o <<= 1) {
    const int uu = __shfl_up(incl, o);
    if ((t & 63) >= o) incl += uu;
  }
  if ((t & 63) == 63) wsum[t >> 6] = incl;
  __syncthreads();
  if (t == 0) {
    int run = 0;
#pragma unroll
    for (int i = 0; i < 8; ++i) {
      const int v = wsum[i];
      wsum[i] = run;
      run += v;
    }
  }
  __syncthreads();
  const int ex = wsum[t >> 6] + incl - sp;
  hist[2 * t] = ex;
  hist[2 * t + 1] = ex + s0;
  // global reservation; delta[k] = absolute_base - bstart[k]
  {
    const int b = 2 * t;
    if (s0) delta[b] = b * RSZ + atomicAdd(&gcur[b * 16], s0) - ex;
    if (s1)
      delta[b + 1] =
          (b + 1) * RSZ + atomicAdd(&gcur[(b + 1) * 16], s1) - (ex + s0);
  }
  __syncthreads();

  // atomic-free placement + per-pos bucket-id fill
#pragma unroll
  for (int i = 0; i < MAXIT; ++i) {
    if (aux[i] >= 0)
      u.s.stage[hist[aux[i] >> 16] + (aux[i] & 0xFFFF)] = rec[i];
  }
  for (int k2 = t; k2 < NB; k2 += 512) {
    const int st = hist[k2];
    const int en = (k2 == NB - 1) ? TILE : hist[k2 + 1];
    for (int p = st; p < en; ++p) u.s.bid[p] = (unsigned short)k2;
  }
  __syncthreads();

  // write-out in position order (L2-merged lines); per-bucket window clamp
  for (int pos = t; pos < TILE; pos += 512) {
    const int bb = u.s.bid[pos];
    const int idx = delta[bb] + pos;
    if (idx < (bb + 1) * RSZ) recs[idx] = u.s.stage[pos];
  }
}

// Per-bucket LDS counting sort + layer-1 agg + layer-2 proj.
// 1024 blocks = 4/CU. 8 lanes/node: oct = (epar<<1)|half, epar in [0,4).
__global__ __launch_bounds__(512, 8) void k_sortagg1(
    const int* __restrict__ gcur, const int* __restrict__ recs,
    const unsigned short* __restrict__ p1h, const float* __restrict__ q1b,
    const float* __restrict__ Wl2, const float* __restrict__ Wr2,
    float* __restrict__ p2, float* __restrict__ r2,
    float* __restrict__ deg_inv) {
  __shared__ int hist[128];    // counts
  __shared__ int nstart[128];  // exclusive scan
  __shared__ int ssort[RSZ];
  __shared__ float sWl[16], sWr[16];
  const int t = threadIdx.x;
  const int kb = blockIdx.x;
  const int b0 = kb * RSZ;
  const int cnt = min(gcur[kb * 16], RSZ);
  if (t < 128) hist[t] = 0;
  if (t < 16) {
    sWl[t] = Wl2[t];
    sWr[t] = Wr2[t];
  }
  __syncthreads();

  int rc[MAXB], ax[MAXB];  // ax = (local<<13) | rank
#pragma unroll
  for (int i = 0; i < MAXB; ++i) {
    const int r = t + i * 512;
    if (r < cnt) {
      const int rv = __builtin_nontemporal_load(recs + b0 + r);
      const int local = rv >> 17;
      const int rank = atomicAdd(&hist[local], 1);
      rc[i] = rv & 0x1FFFF;
      ax[i] = (local << 13) | rank;
    } else {
      ax[i] = -1;
    }
  }
  __syncthreads();

  // single-wave shuffle scan of hist[128] -> nstart (1 barrier)
  if (t < 64) {
    const int a = hist[t], b = hist[t + 64];
    int ia = a, ib = b;
#pragma unroll
    for (int o = 1; o < 64; o <<= 1) {
      const int ua = __shfl_up(ia, o);
      const int ub = __shfl_up(ib, o);
      if (t >= o) {
        ia += ua;
        ib += ub;
      }
    }
    const int tot = __shfl(ia, 63);
    nstart[t] = ia - a;
    nstart[t + 64] = tot + ib - b;
  }
  __syncthreads();

  // atomic-free placement into LDS
#pragma unroll
  for (int i = 0; i < MAXB; ++i) {
    if (ax[i] >= 0) ssort[nstart[ax[i] >> 13] + (ax[i] & 0x1FFF)] = rc[i];
  }
  __syncthreads();

  // aggregation: 8 lanes/node; oct bits = [epar(2) | half(1)]
  const int oct = t & 7;
  const int half = oct & 1;
  const int epar = oct >> 1;  // 0..3: 4-way edge split
  const unsigned short* pb = p1h + half * 8;
#pragma unroll
  for (int p = 0; p < 2; ++p) {
    const int local = p * 64 + (t >> 3);
    if (local >= BKN) continue;
    const int n = kb * BKN + local;
    if (n >= N_NODES) continue;
    const int st = nstart[local];
    const int k = hist[local];

    float acc[8];
#pragma unroll
    for (int i = 0; i < 8; ++i) acc[i] = 0.f;
    int j = epar;
    for (; j + 12 < k; j += 16) {
      const int s0 = ssort[st + j], s1 = ssort[st + j + 4],
                s2 = ssort[st + j + 8], s3 = ssort[st + j + 12];
      const uint4 w0 = *(const uint4*)(pb + (size_t)s0 * 16);
      const uint4 w1 = *(const uint4*)(pb + (size_t)s1 * 16);
      const uint4 w2 = *(const uint4*)(pb + (size_t)s2 * 16);
      const uint4 w3 = *(const uint4*)(pb + (size_t)s3 * 16);
      acc[0] +=
          (bf2f_lo(w0.x) + bf2f_lo(w1.x)) + (bf2f_lo(w2.x) + bf2f_lo(w3.x));
      acc[1] +=
          (bf2f_hi(w0.x) + bf2f_hi(w1.x)) + (bf2f_hi(w2.x) + bf2f_hi(w3.x));
      acc[2] +=
          (bf2f_lo(w0.y) + bf2f_lo(w1.y)) + (bf2f_lo(w2.y) + bf2f_lo(w3.y));
      acc[3] +=
          (bf2f_hi(w0.y) + bf2f_hi(w1.y)) + (bf2f_hi(w2.y) + bf2f_hi(w3.y));
      acc[4] +=
          (bf2f_lo(w0.z) + bf2f_lo(w1.z)) + (bf2f_lo(w2.z) + bf2f_lo(w3.z));
      acc[5] +=
          (bf2f_hi(w0.z) + bf2f_hi(w1.z)) + (bf2f_hi(w2.z) + bf2f_hi(w3.z));
      acc[6] +=
          (bf2f_lo(w0.w) + bf2f_lo(w1.w)) + (bf2f_lo(w2.w) + bf2f_lo(w3.w));
      acc[7] +=
          (bf2f_hi(w0.w) + bf2f_hi(w1.w)) + (bf2f_hi(w2.w) + bf2f_hi(w3.w));
    }
    for (; j < k; j += 4) {
      const uint4 w = *(const uint4*)(pb + (size_t)ssort[st + j] * 16);
      acc[0] += bf2f_lo(w.x);
      acc[1] += bf2f_hi(w.x);
      acc[2] += bf2f_lo(w.y);
      acc[3] += bf2f_hi(w.y);
      acc[4] += bf2f_lo(w.z);
      acc[5] += bf2f_hi(w.z);
      acc[6] += bf2f_lo(w.w);
      acc[7] += bf2f_hi(w.w);
    }
#pragma unroll
    for (int i = 0; i < 8; ++i) {
      acc[i] += __shfl_xor(acc[i], 2);
      acc[i] += __shfl_xor(acc[i], 4);
    }

    if (epar == 0) {
      const float di = 1.f / fmaxf((float)k, 1.f);
      const f32x4* qp = (const f32x4*)(q1b + (size_t)n * 16 + half * 8);
      const f32x4 qa = __builtin_nontemporal_load(qp);
      const f32x4 qb = __builtin_nontemporal_load(qp + 1);
      float h[8];
      h[0] = fmaxf(fmaf(acc[0], di, qa[0]), 0.f);
      h[1] = fmaxf(fmaf(acc[1], di, qa[1]), 0.f);
      h[2] = fmaxf(fmaf(acc[2], di, qa[2]), 0.f);
      h[3] = fmaxf(fmaf(acc[3], di, qa[3]), 0.f);
      h[4] = fmaxf(fmaf(acc[4], di, qb[0]), 0.f);
      h[5] = fmaxf(fmaf(acc[5], di, qb[1]), 0.f);
      h[6] = fmaxf(fmaf(acc[6], di, qb[2]), 0.f);
      h[7] = fmaxf(fmaf(acc[7], di, qb[3]), 0.f);
      float pa = 0.f, pbv = 0.f;
#pragma unroll
      for (int i = 0; i < 8; ++i) {
        pa = fmaf(h[i], sWl[half * 8 + i], pa);
        pbv = fmaf(h[i], sWr[half * 8 + i], pbv);
      }
      pa += __shfl_xor(pa, 1);
      pbv += __shfl_xor(pbv, 1);
      if (half == 0) {
        p2[n] = pa;
        r2[n] = pbv;
        deg_inv[n] = di;
      }
    }
  }
}

// layer-2 aggregation: int4 recs reads (4 records/load), random p2 gather,
// 1 LDS f32 atomicAdd per edge. 1024 blocks = 4/CU.
__global__ __launch_bounds__(512, 8) void k_agg2out(
    const int* __restrict__ gcur, const int* __restrict__ recs,
    const float* __restrict__ p2, const float* __restrict__ r2,
    const float* __restrict__ deg_inv, const float* __restrict__ b2,
    float* __restrict__ out) {
  __shared__ float acc[BKN];
  const int t = threadIdx.x;
  const int kb = blockIdx.x;
  if (t < BKN) acc[t] = 0.f;
  __syncthreads();

  const int b0 = kb * RSZ;
  const int cnt = min(gcur[kb * 16], RSZ);
  for (int base = 4 * t; base < cnt; base += 2048) {
    const i32x4 rv =
        __builtin_nontemporal_load((const i32x4*)(recs + b0 + base));
    if (base + 3 < cnt) {
      const float v0 = p2[rv[0] & 0x1FFFF];
      const float v1 = p2[rv[1] & 0x1FFFF];
      const float v2 = p2[rv[2] & 0x1FFFF];
      const float v3 = p2[rv[3] & 0x1FFFF];
      atomicAdd(&acc[rv[0] >> 17], v0);
      atomicAdd(&acc[rv[1] >> 17], v1);
      atomicAdd(&acc[rv[2] >> 17], v2);
      atomicAdd(&acc[rv[3] >> 17], v3);
    } else {
#pragma unroll
      for (int e2 = 0; e2 < 4; ++e2) {
        if (base + e2 < cnt)
          atomicAdd(&acc[rv[e2] >> 17], p2[rv[e2] & 0x1FFFF]);
      }
    }
  }
  __syncthreads();

  if (t < BKN) {
    const int nn = kb * BKN + t;
    if (nn < N_NODES) out[nn] = fmaf(acc[t], deg_inv[nn], r2[nn] + b2[0]);
  }
}

extern "C" void kernel_launch(void* const* d_in, const int* in_sizes, int n_in,
                              void* d_out, int out_size, void* d_ws,
                              size_t ws_size, hipStream_t stream) {
  const float* x   = (const float*)d_in[0];
  const int*   ei  = (const int*)d_in[1];
  const float* Wl1 = (const float*)d_in[2];
  const float* Wr1 = (const float*)d_in[3];
  const float* b1  = (const float*)d_in[4];
  const float* Wl2 = (const float*)d_in[5];
  const float* Wr2 = (const float*)d_in[6];
  const float* b2  = (const float*)d_in[7];
  float* out = (float*)d_out;

  const size_t N = N_NODES;
  int* wi = (int*)d_ws;
  int* gcur = wi;                                    // NB*16 = 16384 ints
  int* recs = wi + NB * 16;                          // NB*RSZ ints
  unsigned short* p1h = (unsigned short*)(recs + (size_t)NB * RSZ);
  float* q1b     = (float*)(p1h + 16 * N);           // 16N floats
  float* p2      = q1b + 16 * N;
  float* r2      = p2 + N;
  float* deg_inv = r2 + N;

  hipMemsetAsync(gcur, 0, NB * 16 * sizeof(int), stream);
  k_projscatter<<<NTILES, 512, 0, stream>>>(x, ei, Wl1, Wr1, b1, p1h, q1b,
                                            gcur, recs);
  k_sortagg1<<<NB, 512, 0, stream>>>(gcur, recs, p1h, q1b, Wl2, Wr2, p2, r2,
                                     deg_inv);
  k_agg2out<<<NB, 512, 0, stream>>>(gcur, recs, p2, r2, deg_inv, b2, out);
}

// Round 4
// 176.391 us; speedup vs baseline: 1.0175x; 1.0175x over previous
//
#include <hip/hip_runtime.h>

#define N_NODES 100000
#define N_EDGES 3200000
#define NB 1024          // dst buckets
#define BKN 98           // nodes per bucket (1024*98 = 100352)
#define RSZ 3968         // per-bucket record window (mean 3136, +14.9 sigma)
#define TILE 6250        // edges per tile
#define NTILES 512       // 512*6250 == 3.2M exactly
#define MAXIT 13         // ceil(TILE/512)
#define MAXB 8           // ceil(RSZ/512)
#define PROJ_BLOCKS 196  // 196*512 = 100352 proj nodes

typedef float f32x4 __attribute__((ext_vector_type(4)));

// ---------------------------------------------------------------------------
// Atomic-free radix scatter (replaces contended gcur reservation, which the
// round-3 counters implicate: 60us kernel @ 12% VALU / 21% HBM = atomic tail):
//   k_countproj : blocks<512 histogram dst-only per tile -> cnt[tile][bucket]
//                 blocks>=512 proj1 (independent work, same grid, no launch)
//   k_scan      : per bucket, exclusive prefix over 512 tile counts
//                 -> offs[bucket][tile] (+ tot[bucket]); no cross-bucket dep
//                 because buckets keep fixed RSZ windows
//   k_scatter   : re-read edges (tile is L2-warm on same XCD), LDS rank sort,
//                 deterministic write at b*RSZ + offs[b][tile] + local_rank
//   k_sortagg1  : round-2 body (per-bucket LDS sort + L1 agg + L2 proj)
//   k_agg2out   : round-2 body (linear recs + p2 gather + LDS atomicAdd)
// No global atomics anywhere; no memset needed (cnt/offs/tot fully written).
// ---------------------------------------------------------------------------

__device__ __forceinline__ float bf2f_lo(unsigned int w) {
  return __uint_as_float(w << 16);
}
__device__ __forceinline__ float bf2f_hi(unsigned int w) {
  return __uint_as_float(w & 0xFFFF0000u);
}
__device__ __forceinline__ unsigned short f2bf(float f) {
  unsigned int b = __float_as_uint(f);
  return (unsigned short)((b + 0x7FFFu + ((b >> 16) & 1u)) >> 16);
}

// count (blocks 0..511) + proj (blocks 512..707). 708 blocks x 512.
__global__ __launch_bounds__(512, 4) void k_countproj(
    const float* __restrict__ x, const int* __restrict__ ei,
    const float* __restrict__ Wl1, const float* __restrict__ Wr1,
    const float* __restrict__ b1, unsigned short* __restrict__ p1h,
    float* __restrict__ q1b, int* __restrict__ cnt) {
  __shared__ union {
    int hist[1024];
    struct { float Wl[512], Wr[512], b[16]; } w;
  } u;
  const int t = threadIdx.x;
  const int kb = blockIdx.x;

  if (kb < NTILES) {
    // ---- count: dst-only read (12.8 MB total), LDS histogram, 4 KB store
    for (int i = t; i < 1024; i += 512) u.hist[i] = 0;
    __syncthreads();
    const int tb = kb * TILE;
#pragma unroll
    for (int i = 0; i < MAXIT; ++i) {
      const int pos = t + i * 512;
      if (pos < TILE) {
        const int d = ei[N_EDGES + tb + pos];
        atomicAdd(&u.hist[(int)((unsigned)d / (unsigned)BKN)], 1);
      }
    }
    __syncthreads();
    ((int2*)(cnt + kb * NB))[t] = make_int2(u.hist[2 * t], u.hist[2 * t + 1]);
    return;
  }

  // ---- proj: one node per thread
  u.w.Wl[t] = Wl1[t];
  u.w.Wr[t] = Wr1[t];
  if (t < 16) u.w.b[t] = b1[t];
  __syncthreads();

  const int n = (kb - NTILES) * 512 + t;
  if (n >= N_NODES) return;

  float xr[32];
  const float4* xp = (const float4*)(x + (size_t)n * 32);
#pragma unroll
  for (int j = 0; j < 8; ++j) {
    float4 v = xp[j];
    xr[4 * j + 0] = v.x;
    xr[4 * j + 1] = v.y;
    xr[4 * j + 2] = v.z;
    xr[4 * j + 3] = v.w;
  }
  float pv[16], qv[16];
#pragma unroll
  for (int hh = 0; hh < 16; ++hh) {
    float a = 0.f, b = 0.f;
#pragma unroll
    for (int i = 0; i < 32; ++i) {
      a = fmaf(xr[i], u.w.Wl[hh * 32 + i], a);
      b = fmaf(xr[i], u.w.Wr[hh * 32 + i], b);
    }
    pv[hh] = a;
    qv[hh] = b + u.w.b[hh];
  }
  unsigned int w[8];
#pragma unroll
  for (int j = 0; j < 8; ++j)
    w[j] = (unsigned int)f2bf(pv[2 * j]) |
           ((unsigned int)f2bf(pv[2 * j + 1]) << 16);
  uint4* pp = (uint4*)(p1h + (size_t)n * 16);
  pp[0] = make_uint4(w[0], w[1], w[2], w[3]);
  pp[1] = make_uint4(w[4], w[5], w[6], w[7]);
  float4* qp = (float4*)(q1b + (size_t)n * 16);
#pragma unroll
  for (int j = 0; j < 4; ++j)
    qp[j] = make_float4(qv[4 * j], qv[4 * j + 1], qv[4 * j + 2], qv[4 * j + 3]);
}

// per-bucket exclusive prefix over tiles: wave w of block -> bucket.
// 128 blocks x 512 (8 waves = 8 buckets per block). Writes are contiguous.
__global__ __launch_bounds__(512) void k_scan(const int* __restrict__ cnt,
                                              int* __restrict__ offs,
                                              int* __restrict__ tot) {
  const int t = threadIdx.x;
  const int lane = t & 63;
  const int b = blockIdx.x * 8 + (t >> 6);
  int carry = 0;
#pragma unroll
  for (int c = 0; c < 8; ++c) {
    const int tile = c * 64 + lane;
    const int v = cnt[tile * NB + b];
    int incl = v;
#pragma unroll
    for (int o = 1; o < 64; o <<= 1) {
      const int uu = __shfl_up(incl, o);
      if (lane >= o) incl += uu;
    }
    offs[b * NTILES + tile] = carry + incl - v;
    carry += __shfl(incl, 63);
  }
  if (lane == 0) tot[b] = carry;
}

// deterministic tile scatter: LDS rank sort + write at precomputed offsets.
// 512 blocks x 512 = 2/CU; edge tile L2-warm from k_countproj (same XCD).
__global__ __launch_bounds__(512, 4) void k_scatter(const int* __restrict__ ei,
                                                    const int* __restrict__ offs,
                                                    int* __restrict__ recs) {
  __shared__ int hist[1024];   // counts -> exclusive scan (bucket starts)
  __shared__ int delta[NB];    // absolute_base - bstart per bucket
  __shared__ int wsum[8];
  __shared__ int stage[TILE];
  __shared__ unsigned short bid[TILE + 6];
  const int t = threadIdx.x;
  const int kb = blockIdx.x;
  for (int i = t; i < 1024; i += 512) hist[i] = 0;
  __syncthreads();

  const int tb = kb * TILE;
  int rec[MAXIT], aux[MAXIT];  // aux = (bucket<<16) | rank
#pragma unroll
  for (int i = 0; i < MAXIT; ++i) {
    const int pos = t + i * 512;
    if (pos < TILE) {
      const int e = tb + pos;
      const int s = ei[e];
      const int d = ei[N_EDGES + e];
      const int k = (int)((unsigned)d / (unsigned)BKN);
      const int rank = atomicAdd(&hist[k], 1);
      rec[i] = ((d - k * BKN) << 17) | s;
      aux[i] = (k << 16) | rank;
    } else {
      aux[i] = -1;
    }
  }
  __syncthreads();

  // wave-shuffle exclusive scan of hist[1024] (2 barriers)
  const int s0 = hist[2 * t], s1 = hist[2 * t + 1];
  const int sp = s0 + s1;
  int incl = sp;
#pragma unroll
  for (int o = 1; o < 64; o <<= 1) {
    const int uu = __shfl_up(incl, o);
    if ((t & 63) >= o) incl += uu;
  }
  if ((t & 63) == 63) wsum[t >> 6] = incl;
  __syncthreads();
  if (t == 0) {
    int run = 0;
#pragma unroll
    for (int i = 0; i < 8; ++i) {
      const int v = wsum[i];
      wsum[i] = run;
      run += v;
    }
  }
  __syncthreads();
  const int ex = wsum[t >> 6] + incl - sp;
  hist[2 * t] = ex;
  hist[2 * t + 1] = ex + s0;
  // deterministic base from scan output: NO global atomics
  {
    const int b = 2 * t;
    delta[b] = b * RSZ + offs[b * NTILES + kb] - ex;
    delta[b + 1] = (b + 1) * RSZ + offs[(b + 1) * NTILES + kb] - (ex + s0);
  }
  __syncthreads();

  // atomic-free placement + per-pos bucket-id fill
#pragma unroll
  for (int i = 0; i < MAXIT; ++i) {
    if (aux[i] >= 0) stage[hist[aux[i] >> 16] + (aux[i] & 0xFFFF)] = rec[i];
  }
  for (int k2 = t; k2 < NB; k2 += 512) {
    const int st = hist[k2];
    const int en = (k2 == NB - 1) ? TILE : hist[k2 + 1];
    for (int p = st; p < en; ++p) bid[p] = (unsigned short)k2;
  }
  __syncthreads();

  // write-out in position order; per-bucket window clamp (overflow drop)
  for (int pos = t; pos < TILE; pos += 512) {
    const int bb = bid[pos];
    const int idx = delta[bb] + pos;
    if (idx < (bb + 1) * RSZ) recs[idx] = stage[pos];
  }
}

// Per-bucket LDS counting sort + layer-1 agg + layer-2 proj (round-2 body).
// 1024 blocks = 4/CU. 4 lanes/node; quad = (edge-parity<<1)|channel-half.
__global__ __launch_bounds__(512, 8) void k_sortagg1(
    const int* __restrict__ tot, const int* __restrict__ recs,
    const unsigned short* __restrict__ p1h, const float* __restrict__ q1b,
    const float* __restrict__ Wl2, const float* __restrict__ Wr2,
    float* __restrict__ p2, float* __restrict__ r2,
    float* __restrict__ deg_inv) {
  __shared__ int hist[128];
  __shared__ int nstart[128];
  __shared__ int ssort[RSZ];
  __shared__ float sWl[16], sWr[16];
  const int t = threadIdx.x;
  const int kb = blockIdx.x;
  const int b0 = kb * RSZ;
  const int cend = min(tot[kb], RSZ);
  if (t < 128) hist[t] = 0;
  if (t < 16) {
    sWl[t] = Wl2[t];
    sWr[t] = Wr2[t];
  }
  __syncthreads();

  int rc[MAXB], ax[MAXB];  // ax = (local<<13) | rank
#pragma unroll
  for (int i = 0; i < MAXB; ++i) {
    const int r = t + i * 512;
    if (r < cend) {
      const int rv = recs[b0 + r];
      const int local = rv >> 17;
      const int rank = atomicAdd(&hist[local], 1);
      rc[i] = rv & 0x1FFFF;
      ax[i] = (local << 13) | rank;
    } else {
      ax[i] = -1;
    }
  }
  __syncthreads();

  // single-wave shuffle scan of hist[128] -> nstart (1 barrier)
  if (t < 64) {
    const int a = hist[t], b = hist[t + 64];
    int ia = a, ib = b;
#pragma unroll
    for (int o = 1; o < 64; o <<= 1) {
      const int ua = __shfl_up(ia, o);
      const int ub = __shfl_up(ib, o);
      if (t >= o) {
        ia += ua;
        ib += ub;
      }
    }
    const int tt = __shfl(ia, 63);
    nstart[t] = ia - a;
    nstart[t + 64] = tt + ib - b;
  }
  __syncthreads();

  // atomic-free placement into LDS
#pragma unroll
  for (int i = 0; i < MAXB; ++i) {
    if (ax[i] >= 0) ssort[nstart[ax[i] >> 13] + (ax[i] & 0x1FFF)] = rc[i];
  }
  __syncthreads();

  // aggregation: 4 lanes/node; quad = (edge-parity<<1)|channel-half
  const int quad = t & 3;
  const int half = quad & 1;
  const int epar = quad >> 1;
  const unsigned short* pb = p1h + half * 8;
  const int local = t >> 2;  // 0..127 covers BKN=98 in one pass
  if (local < BKN) {
    const int n = kb * BKN + local;
    if (n < N_NODES) {
      const int st = nstart[local];
      const int k = hist[local];

      float acc[8];
#pragma unroll
      for (int i = 0; i < 8; ++i) acc[i] = 0.f;
      int j = epar;
      for (; j + 6 < k; j += 8) {
        const int s0 = ssort[st + j], s1 = ssort[st + j + 2],
                  s2 = ssort[st + j + 4], s3 = ssort[st + j + 6];
        const uint4 w0 = *(const uint4*)(pb + (size_t)s0 * 16);
        const uint4 w1 = *(const uint4*)(pb + (size_t)s1 * 16);
        const uint4 w2 = *(const uint4*)(pb + (size_t)s2 * 16);
        const uint4 w3 = *(const uint4*)(pb + (size_t)s3 * 16);
        acc[0] +=
            (bf2f_lo(w0.x) + bf2f_lo(w1.x)) + (bf2f_lo(w2.x) + bf2f_lo(w3.x));
        acc[1] +=
            (bf2f_hi(w0.x) + bf2f_hi(w1.x)) + (bf2f_hi(w2.x) + bf2f_hi(w3.x));
        acc[2] +=
            (bf2f_lo(w0.y) + bf2f_lo(w1.y)) + (bf2f_lo(w2.y) + bf2f_lo(w3.y));
        acc[3] +=
            (bf2f_hi(w0.y) + bf2f_hi(w1.y)) + (bf2f_hi(w2.y) + bf2f_hi(w3.y));
        acc[4] +=
            (bf2f_lo(w0.z) + bf2f_lo(w1.z)) + (bf2f_lo(w2.z) + bf2f_lo(w3.z));
        acc[5] +=
            (bf2f_hi(w0.z) + bf2f_hi(w1.z)) + (bf2f_hi(w2.z) + bf2f_hi(w3.z));
        acc[6] +=
            (bf2f_lo(w0.w) + bf2f_lo(w1.w)) + (bf2f_lo(w2.w) + bf2f_lo(w3.w));
        acc[7] +=
            (bf2f_hi(w0.w) + bf2f_hi(w1.w)) + (bf2f_hi(w2.w) + bf2f_hi(w3.w));
      }
      for (; j < k; j += 2) {
        const uint4 w = *(const uint4*)(pb + (size_t)ssort[st + j] * 16);
        acc[0] += bf2f_lo(w.x);
        acc[1] += bf2f_hi(w.x);
        acc[2] += bf2f_lo(w.y);
        acc[3] += bf2f_hi(w.y);
        acc[4] += bf2f_lo(w.z);
        acc[5] += bf2f_hi(w.z);
        acc[6] += bf2f_lo(w.w);
        acc[7] += bf2f_hi(w.w);
      }
#pragma unroll
      for (int i = 0; i < 8; ++i) acc[i] += __shfl_xor(acc[i], 2);

      const float di = 1.f / fmaxf((float)k, 1.f);
      const float4* qp = (const float4*)(q1b + (size_t)n * 16 + half * 8);
      const float4 qa = qp[0], qb = qp[1];
      float h[8];
      h[0] = fmaxf(fmaf(acc[0], di, qa.x), 0.f);
      h[1] = fmaxf(fmaf(acc[1], di, qa.y), 0.f);
      h[2] = fmaxf(fmaf(acc[2], di, qa.z), 0.f);
      h[3] = fmaxf(fmaf(acc[3], di, qa.w), 0.f);
      h[4] = fmaxf(fmaf(acc[4], di, qb.x), 0.f);
      h[5] = fmaxf(fmaf(acc[5], di, qb.y), 0.f);
      h[6] = fmaxf(fmaf(acc[6], di, qb.z), 0.f);
      h[7] = fmaxf(fmaf(acc[7], di, qb.w), 0.f);
      float pa = 0.f, pbv = 0.f;
#pragma unroll
      for (int i = 0; i < 8; ++i) {
        pa = fmaf(h[i], sWl[half * 8 + i], pa);
        pbv = fmaf(h[i], sWr[half * 8 + i], pbv);
      }
      pa += __shfl_xor(pa, 1);
      pbv += __shfl_xor(pbv, 1);
      if (quad == 0) {
        p2[n] = pa;
        r2[n] = pbv;
        deg_inv[n] = di;
      }
    }
  }
}

// layer-2 aggregation (round-2 body): linear recs read + random p2 gather +
// 1 LDS f32 atomicAdd per edge. 1024 blocks = 4/CU.
__global__ __launch_bounds__(512, 8) void k_agg2out(
    const int* __restrict__ tot, const int* __restrict__ recs,
    const float* __restrict__ p2, const float* __restrict__ r2,
    const float* __restrict__ deg_inv, const float* __restrict__ b2,
    float* __restrict__ out) {
  __shared__ float acc[BKN];
  const int t = threadIdx.x;
  const int kb = blockIdx.x;
  if (t < BKN) acc[t] = 0.f;
  __syncthreads();

  const int b0 = kb * RSZ;
  const int cnt = min(tot[kb], RSZ);
  int r = t;
  // 4-wide batch: independent gathers in flight before the LDS atomics
  for (; r + 1536 < cnt; r += 2048) {
    const int rv0 = recs[b0 + r];
    const int rv1 = recs[b0 + r + 512];
    const int rv2 = recs[b0 + r + 1024];
    const int rv3 = recs[b0 + r + 1536];
    const float v0 = p2[rv0 & 0x1FFFF];
    const float v1 = p2[rv1 & 0x1FFFF];
    const float v2 = p2[rv2 & 0x1FFFF];
    const float v3 = p2[rv3 & 0x1FFFF];
    atomicAdd(&acc[rv0 >> 17], v0);
    atomicAdd(&acc[rv1 >> 17], v1);
    atomicAdd(&acc[rv2 >> 17], v2);
    atomicAdd(&acc[rv3 >> 17], v3);
  }
  for (; r < cnt; r += 512) {
    const int rv = recs[b0 + r];
    atomicAdd(&acc[rv >> 17], p2[rv & 0x1FFFF]);
  }
  __syncthreads();

  if (t < BKN) {
    const int n = kb * BKN + t;
    if (n < N_NODES) out[n] = fmaf(acc[t], deg_inv[n], r2[n] + b2[0]);
  }
}

extern "C" void kernel_launch(void* const* d_in, const int* in_sizes, int n_in,
                              void* d_out, int out_size, void* d_ws,
                              size_t ws_size, hipStream_t stream) {
  const float* x   = (const float*)d_in[0];
  const int*   ei  = (const int*)d_in[1];
  const float* Wl1 = (const float*)d_in[2];
  const float* Wr1 = (const float*)d_in[3];
  const float* b1  = (const float*)d_in[4];
  const float* Wl2 = (const float*)d_in[5];
  const float* Wr2 = (const float*)d_in[6];
  const float* b2  = (const float*)d_in[7];
  float* out = (float*)d_out;

  const size_t N = N_NODES;
  int* wi = (int*)d_ws;
  int* cnt  = wi;                          // NTILES*NB ints (2 MB)
  int* offs = cnt + NTILES * NB;           // NB*NTILES ints (2 MB)
  int* tot  = offs + NB * NTILES;          // NB ints
  int* recs = tot + NB;                    // NB*RSZ ints
  unsigned short* p1h = (unsigned short*)(recs + (size_t)NB * RSZ);
  float* q1b     = (float*)(p1h + 16 * N); // 16N floats
  float* p2      = q1b + 16 * N;
  float* r2      = p2 + N;
  float* deg_inv = r2 + N;

  k_countproj<<<NTILES + PROJ_BLOCKS, 512, 0, stream>>>(x, ei, Wl1, Wr1, b1,
                                                        p1h, q1b, cnt);
  k_scan<<<NB / 8, 512, 0, stream>>>(cnt, offs, tot);
  k_scatter<<<NTILES, 512, 0, stream>>>(ei, offs, recs);
  k_sortagg1<<<NB, 512, 0, stream>>>(tot, recs, p1h, q1b, Wl2, Wr2, p2, r2,
                                     deg_inv);
  k_agg2out<<<NB, 512, 0, stream>>>(tot, recs, p2, r2, deg_inv, b2, out);
}